// Round 11
// baseline (480.799 us; speedup 1.0000x reference)
//
#include <hip/hip_runtime.h>
#include <math.h>

// Problem constants
#define NQ 8192          // points per batch
#define NP 16384         // total points (B*NQ)
#define H_IN 384
#define W_IN 512
#define HH0 96           // conv out H
#define WW0 128          // conv out W
#define HH1 32           // pooled H
#define WW1 42           // pooled W

// ---------------------------------------------------------------------------
// Kernel 1: transpose conv weights (128,3,7,7) -> wT[tap][oc]
// ---------------------------------------------------------------------------
__global__ void transpose_w_kernel(const float* __restrict__ w, float* __restrict__ wT) {
    int idx = blockIdx.x * 256 + threadIdx.x;
    if (idx < 147 * 128) {
        int tap = idx >> 7;
        int oc  = idx & 127;
        wT[idx] = w[oc * 147 + tap];
    }
}

// ---------------------------------------------------------------------------
// Kernel 2 (v3): conv 7x7 stride 4 pad 3 + bias + relu, channels-last out.
// ---------------------------------------------------------------------------
__global__ __launch_bounds__(256, 4) void conv_kernel(
    const float* __restrict__ frames, const float* __restrict__ wT,
    const float* __restrict__ bias, float* __restrict__ out)
{
    __shared__ float lds[3 * 7 * 136];    // patch [c][kh][col], stride 136
    const int bs  = blockIdx.z;
    const int oh  = blockIdx.y;
    const int ow0 = blockIdx.x * 32;
    const int tid = threadIdx.x;

    for (int idx = tid; idx < 3 * 7 * 134; idx += 256) {
        int c   = idx / 938;               // 7*134
        int rem = idx - c * 938;
        int kh  = rem / 134;
        int col = rem - kh * 134;
        int gy  = oh * 4 - 3 + kh;
        int gx  = ow0 * 4 - 3 + col;
        float v = 0.0f;
        if (gy >= 0 && gy < H_IN && gx >= 0 && gx < W_IN) {
            float t = frames[((size_t)(bs * 3 + c) * H_IN + gy) * W_IN + gx];
            v = 2.0f * (t / 255.0f) - 1.0f;
        }
        lds[(c * 7 + kh) * 136 + col] = v;
    }
    __syncthreads();

    const int oc = tid & 63;
    const int g  = tid >> 6;                // wave id = pixel octet 0..3
    float a0[8], a1[8];
#pragma unroll
    for (int p = 0; p < 8; ++p) { a0[p] = 0.0f; a1[p] = 0.0f; }

#pragma unroll
    for (int c = 0; c < 3; ++c) {
#pragma unroll
        for (int kh = 0; kh < 7; ++kh) {
            const float* row = lds + (c * 7 + kh) * 136 + g * 32;
            float4 r4[9];
#pragma unroll
            for (int j = 0; j < 9; ++j) r4[j] = *(const float4*)(row + j * 4);
            float w0[7], w1v[7];
#pragma unroll
            for (int kw = 0; kw < 7; ++kw) {
                int tap = (c * 7 + kh) * 7 + kw;
                w0[kw]  = wT[tap * 128 + oc];
                w1v[kw] = wT[tap * 128 + oc + 64];
            }
#pragma unroll
            for (int p = 0; p < 8; ++p) {
                const float4 A  = r4[p];
                const float4 Bv = r4[p + 1];
                float s0 = a0[p], s1 = a1[p];
                s0 = fmaf(A.x,  w0[0], s0);  s1 = fmaf(A.x,  w1v[0], s1);
                s0 = fmaf(A.y,  w0[1], s0);  s1 = fmaf(A.y,  w1v[1], s1);
                s0 = fmaf(A.z,  w0[2], s0);  s1 = fmaf(A.z,  w1v[2], s1);
                s0 = fmaf(A.w,  w0[3], s0);  s1 = fmaf(A.w,  w1v[3], s1);
                s0 = fmaf(Bv.x, w0[4], s0);  s1 = fmaf(Bv.x, w1v[4], s1);
                s0 = fmaf(Bv.y, w0[5], s0);  s1 = fmaf(Bv.y, w1v[5], s1);
                s0 = fmaf(Bv.z, w0[6], s0);  s1 = fmaf(Bv.z, w1v[6], s1);
                a0[p] = s0; a1[p] = s1;
            }
        }
    }

    const float b0  = bias[oc];
    const float b1b = bias[oc + 64];
#pragma unroll
    for (int p = 0; p < 8; ++p) {
        int ow = ow0 + g * 8 + p;
        size_t ob = ((size_t)(bs * HH0 + oh) * WW0 + ow) * 128;
        out[ob + oc]      = fmaxf(a0[p] + b0, 0.0f);
        out[ob + oc + 64] = fmaxf(a1[p] + b1b, 0.0f);
    }
}

// ---------------------------------------------------------------------------
// Kernel 3: 3x3/s3 avg pool, channels-last
// ---------------------------------------------------------------------------
__global__ void pool_kernel(const float* __restrict__ in, float* __restrict__ out) {
    int idx = blockIdx.x * 256 + threadIdx.x;
    if (idx >= 4 * HH1 * WW1 * 128) return;
    int c = idx & 127;
    int r = idx >> 7;
    int px = r % WW1; r /= WW1;
    int py = r % HH1;
    int bs = r / HH1;
    float s = 0.0f;
#pragma unroll
    for (int dy = 0; dy < 3; ++dy)
#pragma unroll
        for (int dx = 0; dx < 3; ++dx)
            s += in[(((size_t)bs * HH0 + py * 3 + dy) * WW0 + px * 3 + dx) * 128 + c];
    out[idx] = s / 9.0f;
}

// ---------------------------------------------------------------------------
// Kernel 4 (fused): one tracking level = gather + corr + MLP + head.
// 512 thr = 8 waves = 4 points (1 wave per (point,map)).
// Phase A: bilinear 4x4 patch gather -> 9 window samples in LDS; corr dots
//          (e = mp*64+lane; 0..80 corr, 81..98 self-dots) -> cls[pt][81].
// Phase B: thread = (kc=lane&3 k-chunk, pt=(lane>>2)&3, jg=wvi*4+(lane>>4)
//          -> 8 j's). w1 streamed from L2, deduped across the 16 lanes that
//          share jg. kc-reduce: shfl 1,2. jg-reduce: shfl 16,32 + LDS.
// __launch_bounds__(512,6): ~85-VGPR budget (R4 showed 32-VGPR starvation).
// ---------------------------------------------------------------------------
__global__ __launch_bounds__(512, 6) void level_fused_kernel(
    const float* __restrict__ fm, int hh, int ww,
    const float* __restrict__ cur_in,
    const float* __restrict__ w1, const float* __restrict__ b1,
    const float* __restrict__ wp, const float* __restrict__ bp,
    const float* __restrict__ wvw, const float* __restrict__ bvv,
    float* __restrict__ cur_out,
    const float* __restrict__ vis_in, float* __restrict__ vis_out,
    int is_last)
{
    __shared__ float smem[4 * 2400];     // per point: fl[9*132] ml[9*132] inv[18]
    __shared__ float cls[4 * 84];        // corr [pt][81] (pad 84)
    __shared__ float red[8 * 4 * 10];    // [wave][pt][10]
    const int tid  = threadIdx.x;
    const int wvi  = tid >> 6;                 // 0..7
    const int lane = tid & 63;
    const int ps   = wvi >> 1;                 // point slot 0..3
    const int mp   = wvi & 1;                  // map 0/1
    const int p    = blockIdx.x * 4 + ps;      // global point id
    const int b    = p >> 13;

    float* fl    = smem + ps * 2400;           // [9][132]
    float* ml    = fl + 1188;                  // [9][132]
    float* inv_s = fl + 2376;                  // [18]: 0..8 invf, 9..17 invm

    // ---------------- Phase A: gather + correlate ----------------
    {
        const float2 pxy = *(const float2*)(cur_in + (size_t)p * 2);
        const float wwm1 = (float)(ww - 1);
        const float hhm1 = (float)(hh - 1);
        const float ix = ((pxy.x * 2.0f - 1.0f) + 1.0f) * 0.5f * wwm1;
        const float iy = ((pxy.y * 2.0f - 1.0f) + 1.0f) * 0.5f * hhm1;
        const float x0 = floorf(ix), y0 = floorf(iy);
        const float fx1 = ix - x0, fx0 = 1.0f - fx1;
        const float fy1 = iy - y0, fy0 = 1.0f - fy1;

        int   cx[4], cy[4];
        float vx[4], vy[4];
#pragma unroll
        for (int j = 0; j < 4; ++j) {
            float xc = x0 + (float)(j - 1);
            vx[j] = (xc >= 0.0f && xc <= wwm1) ? 1.0f : 0.0f;
            cx[j] = (int)fminf(fmaxf(xc, 0.0f), wwm1);
            float yc = y0 + (float)(j - 1);
            vy[j] = (yc >= 0.0f && yc <= hhm1) ? 1.0f : 0.0f;
            cy[j] = (int)fminf(fmaxf(yc, 0.0f), hhm1);
        }
        float cwx[6], cwy[6];
#pragma unroll
        for (int t = 0; t < 3; ++t) {
            cwx[t * 2 + 0] = fx0 * vx[t]; cwx[t * 2 + 1] = fx1 * vx[t + 1];
            cwy[t * 2 + 0] = fy0 * vy[t]; cwy[t * 2 + 1] = fy1 * vy[t + 1];
        }

        const float2* src = (const float2*)fm + (size_t)(b * 2 + mp) * hh * ww * 64;
        float* dst = mp ? ml : fl;
        float2 P[4][4];
#pragma unroll
        for (int j = 0; j < 4; ++j)
#pragma unroll
            for (int i = 0; i < 4; ++i)
                P[j][i] = src[(cy[j] * ww + cx[i]) * 64 + lane];
#pragma unroll
        for (int ky = 0; ky < 3; ++ky)
#pragma unroll
            for (int kx = 0; kx < 3; ++kx) {
                float wA = cwy[ky * 2 + 0] * cwx[kx * 2 + 0];
                float wB = cwy[ky * 2 + 0] * cwx[kx * 2 + 1];
                float wC = cwy[ky * 2 + 1] * cwx[kx * 2 + 0];
                float wD = cwy[ky * 2 + 1] * cwx[kx * 2 + 1];
                float sx = wA * P[ky][kx].x;
                sx = fmaf(wB, P[ky][kx + 1].x, sx);
                sx = fmaf(wC, P[ky + 1][kx].x, sx);
                sx = fmaf(wD, P[ky + 1][kx + 1].x, sx);
                float sy = wA * P[ky][kx].y;
                sy = fmaf(wB, P[ky][kx + 1].y, sy);
                sy = fmaf(wC, P[ky + 1][kx].y, sy);
                sy = fmaf(wD, P[ky + 1][kx + 1].y, sy);
                *(float2*)(dst + (ky * 3 + kx) * 132 + 2 * lane) = make_float2(sx, sy);
            }
    }
    __syncthreads();

    {
        // dots: this wave handles e = mp*64 + lane (0..98 valid)
        const int e = mp * 64 + lane;
        float s = 0.0f;
        {
            const float *rA, *rB;
            if (e < 81)      { rA = fl + (e / 9) * 132; rB = ml + (e % 9) * 132; }
            else if (e < 90) { rA = fl + (e - 81) * 132; rB = rA; }
            else             { int em = e - 90; if (em > 8) em = 8;
                               rA = ml + em * 132; rB = rA; }
#pragma unroll
            for (int c = 0; c < 128; c += 4) {
                float4 a  = *(const float4*)(rA + c);
                float4 bb = *(const float4*)(rB + c);
                s += a.x * bb.x; s += a.y * bb.y; s += a.z * bb.z; s += a.w * bb.w;
            }
        }
        if (e >= 81 && e < 90)      inv_s[e - 81]     = 1.0f / fmaxf(sqrtf(s), 1e-12f);
        else if (e >= 90 && e < 99) inv_s[e - 90 + 9] = 1.0f / fmaxf(sqrtf(s), 1e-12f);
        __syncthreads();
        if (e < 81)
            cls[ps * 84 + e] = s * inv_s[e / 9] * inv_s[9 + e % 9];
    }
    __syncthreads();

    // ---------------- Phase B: MLP + head ----------------
    const int kc  = lane & 3;             // k-chunk 0..3
    const int pt  = (lane >> 2) & 3;      // point slot 0..3
    const int jgl = lane >> 4;            // 0..3
    const int jg  = wvi * 4 + jgl;        // 0..31
    const int j0  = jg * 8;

    float h[8];
#pragma unroll
    for (int j = 0; j < 8; ++j) h[j] = 0.0f;

    {
        const float* wbase = w1 + j0;
        const float* crow  = cls + pt * 84;
        const int i0   = kc * 20;
        const int icnt = (kc == 3) ? 21 : 20;
#pragma unroll 4
        for (int ii = 0; ii < icnt; ++ii) {
            const int i = i0 + ii;
            const float4 wa = *(const float4*)(wbase + i * 256);
            const float4 wb = *(const float4*)(wbase + i * 256 + 4);
            const float cv = crow[i];
            h[0] = fmaf(cv, wa.x, h[0]); h[1] = fmaf(cv, wa.y, h[1]);
            h[2] = fmaf(cv, wa.z, h[2]); h[3] = fmaf(cv, wa.w, h[3]);
            h[4] = fmaf(cv, wb.x, h[4]); h[5] = fmaf(cv, wb.y, h[5]);
            h[6] = fmaf(cv, wb.z, h[6]); h[7] = fmaf(cv, wb.w, h[7]);
        }
    }
    // reduce over kc (lane bits 0..1) -> every lane holds full h for (pt,jg)
#pragma unroll
    for (int j = 0; j < 8; ++j) {
        h[j] += __shfl_xor(h[j], 1);
        h[j] += __shfl_xor(h[j], 2);
    }

    // stage 2: 10 outputs partial over this thread's 8 j's
    float b1v[8];
    {
        const float4* bp4 = (const float4*)(b1 + j0);
        const float4 ba = bp4[0], bb = bp4[1];
        b1v[0] = ba.x; b1v[1] = ba.y; b1v[2] = ba.z; b1v[3] = ba.w;
        b1v[4] = bb.x; b1v[5] = bb.y; b1v[6] = bb.z; b1v[7] = bb.w;
    }
    float pl[10];
#pragma unroll
    for (int o = 0; o < 10; ++o) pl[o] = 0.0f;
#pragma unroll
    for (int j = 0; j < 8; ++j) {
        const float hv = fmaxf(h[j] + b1v[j], 0.0f);
        const float* wr = wp + (j0 + j) * 9;
#pragma unroll
        for (int o = 0; o < 9; ++o) pl[o] = fmaf(hv, wr[o], pl[o]);
        pl[9] = fmaf(hv, wvw[j0 + j], pl[9]);
    }
    // reduce over jgl (lane bits 4..5)
#pragma unroll
    for (int o = 0; o < 10; ++o) {
        pl[o] += __shfl_xor(pl[o], 16);
        pl[o] += __shfl_xor(pl[o], 32);
    }
    if (lane == pt * 4) {
#pragma unroll
        for (int o = 0; o < 10; ++o) red[(wvi * 4 + pt) * 10 + o] = pl[o];
    }
    __syncthreads();

    if (tid < 4) {
        const int pw = blockIdx.x * 4 + tid;
        float fo[10];
#pragma unroll
        for (int o = 0; o < 10; ++o) {
            float v = 0.0f;
#pragma unroll
            for (int w = 0; w < 8; ++w) v += red[(w * 4 + tid) * 10 + o];
            fo[o] = v;
        }
        float lg[9];
#pragma unroll
        for (int o = 0; o < 9; ++o) lg[o] = fo[o] + bp[o];
        float mx = lg[0];
#pragma unroll
        for (int o = 1; o < 9; ++o) mx = fmaxf(mx, lg[o]);
        float ex[9], sum = 0.0f;
#pragma unroll
        for (int o = 0; o < 9; ++o) { ex[o] = expf(lg[o] - mx); sum += ex[o]; }
#pragma unroll
        for (int o = 0; o < 9; ++o) ex[o] = ex[o] / sum;

        const float vis = 1.0f / (1.0f + expf(-(fo[9] + bvv[0])));

        const float wwm1 = (float)(ww - 1);
        const float hhm1 = (float)(hh - 1);
        const float ax = 1.0f / wwm1;
        const float ay = 1.0f / hhm1;
        const float r0 = ex[0] + ex[1] + ex[2];
        const float r2 = ex[6] + ex[7] + ex[8];
        const float c0 = ex[0] + ex[3] + ex[6];
        const float c2 = ex[2] + ex[5] + ex[8];
        const float dx = r0 * (-ax) + r2 * ax;
        const float dy = c0 * (-ay) + c2 * ay;

        const float2 pq = *(const float2*)(cur_in + (size_t)pw * 2);
        *(float2*)(cur_out + (size_t)pw * 2) = make_float2(pq.x + dx, pq.y + dy);
        vis_out[pw] = is_last ? (vis_in[pw] + vis) * 0.5f : vis;
    }
}

// ---------------------------------------------------------------------------
extern "C" void kernel_launch(void* const* d_in, const int* in_sizes, int n_in,
                              void* d_out, int out_size, void* d_ws, size_t ws_size,
                              hipStream_t stream) {
    (void)in_sizes; (void)n_in; (void)out_size; (void)ws_size;
    const float* queries = (const float*)d_in[0];
    const float* frames  = (const float*)d_in[1];
    const float* conv_w  = (const float*)d_in[2];
    const float* conv_b  = (const float*)d_in[3];
    const float* w1      = (const float*)d_in[4];
    const float* b1      = (const float*)d_in[5];
    const float* wp      = (const float*)d_in[6];
    const float* bp      = (const float*)d_in[7];
    const float* wvw     = (const float*)d_in[8];
    const float* bvv     = (const float*)d_in[9];
    float* out = (float*)d_out;

    // ws layout (floats): fm0 | fm1 | wT | cur_ws | vis_ws (~28 MB)
    float* ws     = (float*)d_ws;
    float* fm0    = ws;                         // 6291456
    float* fm1    = fm0 + 6291456;              // 688128
    float* wT     = fm1 + 688128;               // 18816
    float* cur_ws = wT + 18816;                 // 32768
    float* vis_ws = cur_ws + 32768;             // 16384

    transpose_w_kernel<<<74, 256, 0, stream>>>(conv_w, wT);
    conv_kernel<<<dim3(4, HH0, 4), 256, 0, stream>>>(frames, wT, conv_b, fm0);
    pool_kernel<<<2688, 256, 0, stream>>>(fm0, fm1);

    // level 0: coarse map
    level_fused_kernel<<<4096, 512, 0, stream>>>(fm1, HH1, WW1, queries,
                                                 w1, b1, wp, bp, wvw, bvv,
                                                 cur_ws, nullptr, vis_ws, 0);
    // level 1: fine map, final outputs
    level_fused_kernel<<<4096, 512, 0, stream>>>(fm0, HH0, WW0, cur_ws,
                                                 w1, b1, wp, bp, wvw, bvv,
                                                 out, vis_ws, out + 32768, 1);
}

// Round 12
// 236.789 us; speedup vs baseline: 2.0305x; 2.0305x over previous
//
#include <hip/hip_runtime.h>
#include <math.h>

// Problem constants
#define NQ 8192          // points per batch
#define NP 16384         // total points (B*NQ)
#define H_IN 384
#define W_IN 512
#define HH0 96           // conv out H
#define WW0 128          // conv out W
#define HH1 32           // pooled H
#define WW1 42           // pooled W

// ---------------------------------------------------------------------------
// Kernel 1: transpose conv weights (128,3,7,7) -> wT[tap][oc]
// ---------------------------------------------------------------------------
__global__ void transpose_w_kernel(const float* __restrict__ w, float* __restrict__ wT) {
    int idx = blockIdx.x * 256 + threadIdx.x;
    if (idx < 147 * 128) {
        int tap = idx >> 7;
        int oc  = idx & 127;
        wT[idx] = w[oc * 147 + tap];
    }
}

// ---------------------------------------------------------------------------
// Kernel 2 (v3): conv 7x7 stride 4 pad 3 + bias + relu, channels-last out.
// ---------------------------------------------------------------------------
__global__ __launch_bounds__(256, 4) void conv_kernel(
    const float* __restrict__ frames, const float* __restrict__ wT,
    const float* __restrict__ bias, float* __restrict__ out)
{
    __shared__ float lds[3 * 7 * 136];    // patch [c][kh][col], stride 136
    const int bs  = blockIdx.z;
    const int oh  = blockIdx.y;
    const int ow0 = blockIdx.x * 32;
    const int tid = threadIdx.x;

    for (int idx = tid; idx < 3 * 7 * 134; idx += 256) {
        int c   = idx / 938;               // 7*134
        int rem = idx - c * 938;
        int kh  = rem / 134;
        int col = rem - kh * 134;
        int gy  = oh * 4 - 3 + kh;
        int gx  = ow0 * 4 - 3 + col;
        float v = 0.0f;
        if (gy >= 0 && gy < H_IN && gx >= 0 && gx < W_IN) {
            float t = frames[((size_t)(bs * 3 + c) * H_IN + gy) * W_IN + gx];
            v = 2.0f * (t / 255.0f) - 1.0f;
        }
        lds[(c * 7 + kh) * 136 + col] = v;
    }
    __syncthreads();

    const int oc = tid & 63;
    const int g  = tid >> 6;                // wave id = pixel octet 0..3
    float a0[8], a1[8];
#pragma unroll
    for (int p = 0; p < 8; ++p) { a0[p] = 0.0f; a1[p] = 0.0f; }

#pragma unroll
    for (int c = 0; c < 3; ++c) {
#pragma unroll
        for (int kh = 0; kh < 7; ++kh) {
            const float* row = lds + (c * 7 + kh) * 136 + g * 32;
            float4 r4[9];
#pragma unroll
            for (int j = 0; j < 9; ++j) r4[j] = *(const float4*)(row + j * 4);
            float w0[7], w1v[7];
#pragma unroll
            for (int kw = 0; kw < 7; ++kw) {
                int tap = (c * 7 + kh) * 7 + kw;
                w0[kw]  = wT[tap * 128 + oc];
                w1v[kw] = wT[tap * 128 + oc + 64];
            }
#pragma unroll
            for (int p = 0; p < 8; ++p) {
                const float4 A  = r4[p];
                const float4 Bv = r4[p + 1];
                float s0 = a0[p], s1 = a1[p];
                s0 = fmaf(A.x,  w0[0], s0);  s1 = fmaf(A.x,  w1v[0], s1);
                s0 = fmaf(A.y,  w0[1], s0);  s1 = fmaf(A.y,  w1v[1], s1);
                s0 = fmaf(A.z,  w0[2], s0);  s1 = fmaf(A.z,  w1v[2], s1);
                s0 = fmaf(A.w,  w0[3], s0);  s1 = fmaf(A.w,  w1v[3], s1);
                s0 = fmaf(Bv.x, w0[4], s0);  s1 = fmaf(Bv.x, w1v[4], s1);
                s0 = fmaf(Bv.y, w0[5], s0);  s1 = fmaf(Bv.y, w1v[5], s1);
                s0 = fmaf(Bv.z, w0[6], s0);  s1 = fmaf(Bv.z, w1v[6], s1);
                a0[p] = s0; a1[p] = s1;
            }
        }
    }

    const float b0  = bias[oc];
    const float b1b = bias[oc + 64];
#pragma unroll
    for (int p = 0; p < 8; ++p) {
        int ow = ow0 + g * 8 + p;
        size_t ob = ((size_t)(bs * HH0 + oh) * WW0 + ow) * 128;
        out[ob + oc]      = fmaxf(a0[p] + b0, 0.0f);
        out[ob + oc + 64] = fmaxf(a1[p] + b1b, 0.0f);
    }
}

// ---------------------------------------------------------------------------
// Kernel 3: 3x3/s3 avg pool, channels-last
// ---------------------------------------------------------------------------
__global__ void pool_kernel(const float* __restrict__ in, float* __restrict__ out) {
    int idx = blockIdx.x * 256 + threadIdx.x;
    if (idx >= 4 * HH1 * WW1 * 128) return;
    int c = idx & 127;
    int r = idx >> 7;
    int px = r % WW1; r /= WW1;
    int py = r % HH1;
    int bs = r / HH1;
    float s = 0.0f;
#pragma unroll
    for (int dy = 0; dy < 3; ++dy)
#pragma unroll
        for (int dx = 0; dx < 3; ++dx)
            s += in[(((size_t)bs * HH0 + py * 3 + dy) * WW0 + px * 3 + dx) * 128 + c];
    out[idx] = s / 9.0f;
}

// ---------------------------------------------------------------------------
// Kernel 4: sample+corr. One wave per (point,map); 512 thr = 4 points.
// ---------------------------------------------------------------------------
__global__ __launch_bounds__(512) void sample_kernel(
    const float* __restrict__ fm, int hh, int ww,
    const float* __restrict__ cur_in, float* __restrict__ corr_out)
{
    __shared__ float smem[4 * 2400];
    const int tid  = threadIdx.x;
    const int wvi  = tid >> 6;                 // 0..7
    const int lane = tid & 63;
    const int ps   = wvi >> 1;                 // point slot 0..3
    const int mp   = wvi & 1;                  // map 0/1
    const int p    = blockIdx.x * 4 + ps;      // global point id
    const int b    = p >> 13;

    float* fl    = smem + ps * 2400;           // [9][132]
    float* ml    = fl + 1188;                  // [9][132]
    float* inv_s = fl + 2376;                  // [18]: 0..8 invf, 9..17 invm

    const float2 pxy = *(const float2*)(cur_in + (size_t)p * 2);
    const float wwm1 = (float)(ww - 1);
    const float hhm1 = (float)(hh - 1);
    const float ix = ((pxy.x * 2.0f - 1.0f) + 1.0f) * 0.5f * wwm1;
    const float iy = ((pxy.y * 2.0f - 1.0f) + 1.0f) * 0.5f * hhm1;
    const float x0 = floorf(ix), y0 = floorf(iy);
    const float fx1 = ix - x0, fx0 = 1.0f - fx1;
    const float fy1 = iy - y0, fy0 = 1.0f - fy1;

    int   cx[4], cy[4];
    float vx[4], vy[4];
#pragma unroll
    for (int j = 0; j < 4; ++j) {
        float xc = x0 + (float)(j - 1);
        vx[j] = (xc >= 0.0f && xc <= wwm1) ? 1.0f : 0.0f;
        cx[j] = (int)fminf(fmaxf(xc, 0.0f), wwm1);
        float yc = y0 + (float)(j - 1);
        vy[j] = (yc >= 0.0f && yc <= hhm1) ? 1.0f : 0.0f;
        cy[j] = (int)fminf(fmaxf(yc, 0.0f), hhm1);
    }
    float cwx[6], cwy[6];
#pragma unroll
    for (int t = 0; t < 3; ++t) {
        cwx[t * 2 + 0] = fx0 * vx[t]; cwx[t * 2 + 1] = fx1 * vx[t + 1];
        cwy[t * 2 + 0] = fy0 * vy[t]; cwy[t * 2 + 1] = fy1 * vy[t + 1];
    }

    // gather this wave's map: 4x4 float2 patch -> 9 window samples in LDS
    {
        const float2* src = (const float2*)fm + (size_t)(b * 2 + mp) * hh * ww * 64;
        float* dst = mp ? ml : fl;
        float2 P[4][4];
#pragma unroll
        for (int j = 0; j < 4; ++j)
#pragma unroll
            for (int i = 0; i < 4; ++i)
                P[j][i] = src[(cy[j] * ww + cx[i]) * 64 + lane];
#pragma unroll
        for (int ky = 0; ky < 3; ++ky)
#pragma unroll
            for (int kx = 0; kx < 3; ++kx) {
                float wA = cwy[ky * 2 + 0] * cwx[kx * 2 + 0];
                float wB = cwy[ky * 2 + 0] * cwx[kx * 2 + 1];
                float wC = cwy[ky * 2 + 1] * cwx[kx * 2 + 0];
                float wD = cwy[ky * 2 + 1] * cwx[kx * 2 + 1];
                float sx = wA * P[ky][kx].x;
                sx = fmaf(wB, P[ky][kx + 1].x, sx);
                sx = fmaf(wC, P[ky + 1][kx].x, sx);
                sx = fmaf(wD, P[ky + 1][kx + 1].x, sx);
                float sy = wA * P[ky][kx].y;
                sy = fmaf(wB, P[ky][kx + 1].y, sy);
                sy = fmaf(wC, P[ky + 1][kx].y, sy);
                sy = fmaf(wD, P[ky + 1][kx + 1].y, sy);
                *(float2*)(dst + (ky * 3 + kx) * 132 + 2 * lane) = make_float2(sx, sy);
            }
    }
    __syncthreads();

    // dots: this wave handles e = mp*64 + lane (0..98 valid)
    const int e = mp * 64 + lane;
    float s = 0.0f;
    {
        const float *rA, *rB;
        if (e < 81)      { rA = fl + (e / 9) * 132; rB = ml + (e % 9) * 132; }
        else if (e < 90) { rA = fl + (e - 81) * 132; rB = rA; }
        else             { int em = e - 90; if (em > 8) em = 8;
                           rA = ml + em * 132; rB = rA; }
#pragma unroll
        for (int c = 0; c < 128; c += 4) {
            float4 a  = *(const float4*)(rA + c);
            float4 bb = *(const float4*)(rB + c);
            s += a.x * bb.x; s += a.y * bb.y; s += a.z * bb.z; s += a.w * bb.w;
        }
    }
    if (e >= 81 && e < 90)      inv_s[e - 81]     = 1.0f / fmaxf(sqrtf(s), 1e-12f);
    else if (e >= 90 && e < 99) inv_s[e - 90 + 9] = 1.0f / fmaxf(sqrtf(s), 1e-12f);
    __syncthreads();

    if (e < 81)
        corr_out[(size_t)p * 81 + e] = s * inv_s[e / 9] * inv_s[9 + e % 9];
}

// ---------------------------------------------------------------------------
// Kernel 5 (v8): MLP + head. 64 points/block (256 blocks), 256 thr.
// lane = point (all w1/wp reads WAVE-UNIFORM -> LDS broadcast, conflict-free,
// zero redundancy); wave = 64-wide j-slice; h[64] in registers.
// cls stride 85 (coprime with 32) -> conflict-free lane-varying cv reads.
// __launch_bounds__(256,1): full register budget, no spill of h[64].
// ---------------------------------------------------------------------------
__global__ __launch_bounds__(256, 1) void mlp_kernel(
    const float* __restrict__ corr, const float* __restrict__ cur_in,
    const float* __restrict__ w1, const float* __restrict__ b1,
    const float* __restrict__ wp, const float* __restrict__ bp,
    const float* __restrict__ wvw, const float* __restrict__ bvv,
    int hh, int ww,
    float* __restrict__ cur_out,
    const float* __restrict__ vis_in, float* __restrict__ vis_out,
    int is_last)
{
    __shared__ float w1L[81 * 256];     // 82944 B
    __shared__ float clsL[64 * 85];     // 21760 B, stride 85 (bank-coprime)
    __shared__ float wpL[256 * 9];      // 9216 B
    __shared__ float wvL[256];          // 1024 B
    __shared__ float b1L[256];          // 1024 B
    __shared__ float red[256 * 10];     // 10240 B  (total ~126 KB)
    const int tid   = threadIdx.x;
    const int wvi   = tid >> 6;         // wave -> j-slice [wvi*64, wvi*64+64)
    const int lane  = tid & 63;         // lane -> point
    const int j0    = wvi * 64;
    const int pbase = blockIdx.x * 64;

    // stage w1 (coalesced float4)
    {
        const float4* src = (const float4*)w1;
        float4*       dst = (float4*)w1L;
        for (int idx = tid; idx < 5184; idx += 256) dst[idx] = src[idx];
    }
    // stage cls (coalesced read, stride-85 write)
    for (int idx = tid; idx < 64 * 81; idx += 256) {
        int pt = idx / 81, i = idx - pt * 81;
        clsL[pt * 85 + i] = corr[(size_t)pbase * 81 + idx];
    }
    for (int idx = tid; idx < 2304; idx += 256) wpL[idx] = wp[idx];
    if (tid < 256) { wvL[tid] = wvw[tid]; b1L[tid] = b1[tid]; }
    __syncthreads();

    // stage 1: h[64] for this lane's point, this wave's j-slice
    float h[64];
#pragma unroll
    for (int jj = 0; jj < 64; ++jj) h[jj] = 0.0f;

    const float* crow = clsL + lane * 85;
    for (int i = 0; i < 81; ++i) {
        const float cv = crow[i];
        const float4* wrow = (const float4*)(w1L + i * 256 + j0);  // uniform
#pragma unroll
        for (int q = 0; q < 16; ++q) {
            const float4 w4 = wrow[q];
            h[q * 4 + 0] = fmaf(cv, w4.x, h[q * 4 + 0]);
            h[q * 4 + 1] = fmaf(cv, w4.y, h[q * 4 + 1]);
            h[q * 4 + 2] = fmaf(cv, w4.z, h[q * 4 + 2]);
            h[q * 4 + 3] = fmaf(cv, w4.w, h[q * 4 + 3]);
        }
    }

    // stage 2: 10 outputs partial over this wave's 64 j's (per-lane point)
    float pl[10];
#pragma unroll
    for (int o = 0; o < 10; ++o) pl[o] = 0.0f;
#pragma unroll
    for (int jj = 0; jj < 64; ++jj) {
        const float hv = fmaxf(h[jj] + b1L[j0 + jj], 0.0f);
        const float* wr = wpL + (j0 + jj) * 9;          // uniform
#pragma unroll
        for (int o = 0; o < 9; ++o) pl[o] = fmaf(hv, wr[o], pl[o]);
        pl[9] = fmaf(hv, wvL[j0 + jj], pl[9]);
    }
#pragma unroll
    for (int o = 0; o < 10; ++o) red[(wvi * 64 + lane) * 10 + o] = pl[o];
    __syncthreads();

    // cross-wave sum + head, lane = point (all 64 lanes of wave 0 busy)
    if (wvi == 0) {
        const int p = pbase + lane;
        float fo[10];
#pragma unroll
        for (int o = 0; o < 10; ++o) {
            float v = red[lane * 10 + o];
            v += red[(64 + lane) * 10 + o];
            v += red[(128 + lane) * 10 + o];
            v += red[(192 + lane) * 10 + o];
            fo[o] = v;
        }
        float lg[9];
#pragma unroll
        for (int o = 0; o < 9; ++o) lg[o] = fo[o] + bp[o];
        float mx = lg[0];
#pragma unroll
        for (int o = 1; o < 9; ++o) mx = fmaxf(mx, lg[o]);
        float ex[9], sum = 0.0f;
#pragma unroll
        for (int o = 0; o < 9; ++o) { ex[o] = expf(lg[o] - mx); sum += ex[o]; }
#pragma unroll
        for (int o = 0; o < 9; ++o) ex[o] = ex[o] / sum;

        const float vis = 1.0f / (1.0f + expf(-(fo[9] + bvv[0])));

        const float wwm1 = (float)(ww - 1);
        const float hhm1 = (float)(hh - 1);
        const float ax = 1.0f / wwm1;
        const float ay = 1.0f / hhm1;
        const float r0 = ex[0] + ex[1] + ex[2];
        const float r2 = ex[6] + ex[7] + ex[8];
        const float c0 = ex[0] + ex[3] + ex[6];
        const float c2 = ex[2] + ex[5] + ex[8];
        const float dx = r0 * (-ax) + r2 * ax;
        const float dy = c0 * (-ay) + c2 * ay;

        const float2 pq = *(const float2*)(cur_in + (size_t)p * 2);
        *(float2*)(cur_out + (size_t)p * 2) = make_float2(pq.x + dx, pq.y + dy);
        vis_out[p] = is_last ? (vis_in[p] + vis) * 0.5f : vis;
    }
}

// ---------------------------------------------------------------------------
extern "C" void kernel_launch(void* const* d_in, const int* in_sizes, int n_in,
                              void* d_out, int out_size, void* d_ws, size_t ws_size,
                              hipStream_t stream) {
    (void)in_sizes; (void)n_in; (void)out_size; (void)ws_size;
    const float* queries = (const float*)d_in[0];
    const float* frames  = (const float*)d_in[1];
    const float* conv_w  = (const float*)d_in[2];
    const float* conv_b  = (const float*)d_in[3];
    const float* w1      = (const float*)d_in[4];
    const float* b1      = (const float*)d_in[5];
    const float* wp      = (const float*)d_in[6];
    const float* bp      = (const float*)d_in[7];
    const float* wvw     = (const float*)d_in[8];
    const float* bvv     = (const float*)d_in[9];
    float* out = (float*)d_out;

    // ws layout (floats): fm0 | fm1 | wT | cur_ws | vis_ws | corrws (~33.5 MB)
    float* ws     = (float*)d_ws;
    float* fm0    = ws;                         // 6291456
    float* fm1    = fm0 + 6291456;              // 688128
    float* wT     = fm1 + 688128;               // 18816
    float* cur_ws = wT + 18816;                 // 32768
    float* vis_ws = cur_ws + 32768;             // 16384
    float* corrws = vis_ws + 16384;             // 16384*81 = 1327104

    transpose_w_kernel<<<74, 256, 0, stream>>>(conv_w, wT);
    conv_kernel<<<dim3(4, HH0, 4), 256, 0, stream>>>(frames, wT, conv_b, fm0);
    pool_kernel<<<2688, 256, 0, stream>>>(fm0, fm1);

    // level 0: coarse map
    sample_kernel<<<4096, 512, 0, stream>>>(fm1, HH1, WW1, queries, corrws);
    mlp_kernel<<<256, 256, 0, stream>>>(corrws, queries, w1, b1, wp, bp, wvw, bvv,
                                        HH1, WW1, cur_ws, nullptr, vis_ws, 0);
    // level 1: fine map, final outputs
    sample_kernel<<<4096, 512, 0, stream>>>(fm0, HH0, WW0, cur_ws, corrws);
    mlp_kernel<<<256, 256, 0, stream>>>(corrws, cur_ws, w1, b1, wp, bp, wvw, bvv,
                                        HH0, WW0, out, vis_ws, out + 32768, 1);
}